// Round 1
// baseline (1508.449 us; speedup 1.0000x reference)
//
#include <hip/hip_runtime.h>
#include <hip/hip_bf16.h>

// Problem constants (fixed by the reference).
constexpr int N_ = 262144;   // nodes
constexpr int C_ = 256;      // channels
constexpr int P_ = 4096;     // patches

// ---------------------------------------------------------------------------
// Kernel 1: segment mean (sorted batch, binary-search range) + LayerNorm
// One block per patch, 256 threads = 256 channels.
// ---------------------------------------------------------------------------
__global__ __launch_bounds__(256) void seg_mean_ln(
    const float* __restrict__ dg, const int* __restrict__ batch,
    const float* __restrict__ w, const float* __restrict__ b,
    float* __restrict__ g_out)
{
    const int p   = blockIdx.x;
    const int tid = threadIdx.x;

    // lower_bound(batch, p) and lower_bound(batch, p+1) — uniform across threads
    int lo = 0, hi = N_;
    while (lo < hi) { int mid = (lo + hi) >> 1; if (batch[mid] < p) lo = mid + 1; else hi = mid; }
    const int start = lo;
    hi = N_;
    while (lo < hi) { int mid = (lo + hi) >> 1; if (batch[mid] < p + 1) lo = mid + 1; else hi = mid; }
    const int end = lo;

    float s = 0.f;
    for (int i = start; i < end; ++i)
        s += dg[(size_t)i * C_ + tid];          // coalesced across threads

    const float cnt = (float)(end - start);
    const float v = (cnt > 0.f) ? (s / cnt) : 0.f;

    // Block-wide LayerNorm over the 256 channel values (one per thread)
    __shared__ float red[8];
    float t = v, tq = v * v;
    #pragma unroll
    for (int off = 32; off > 0; off >>= 1) {
        t  += __shfl_xor(t,  off);
        tq += __shfl_xor(tq, off);
    }
    const int wid = tid >> 6;
    if ((tid & 63) == 0) { red[wid] = t; red[4 + wid] = tq; }
    __syncthreads();
    const float S  = red[0] + red[1] + red[2] + red[3];
    const float SQ = red[4] + red[5] + red[6] + red[7];
    const float mu  = S * (1.f / C_);
    const float var = SQ * (1.f / C_) - mu * mu;
    const float r   = rsqrtf(var + 1e-5f);
    g_out[(size_t)p * C_ + tid] = (v - mu) * r * w[tid] + b[tid];
}

// ---------------------------------------------------------------------------
// Kernel 2: per-patch LayerNorm (P x C), one block per patch
// ---------------------------------------------------------------------------
__global__ __launch_bounds__(256) void patch_ln(
    const float* __restrict__ in,
    const float* __restrict__ w, const float* __restrict__ b,
    float* __restrict__ out)
{
    const int p   = blockIdx.x;
    const int tid = threadIdx.x;
    const float v = in[(size_t)p * C_ + tid];

    __shared__ float red[8];
    float t = v, tq = v * v;
    #pragma unroll
    for (int off = 32; off > 0; off >>= 1) {
        t  += __shfl_xor(t,  off);
        tq += __shfl_xor(tq, off);
    }
    const int wid = tid >> 6;
    if ((tid & 63) == 0) { red[wid] = t; red[4 + wid] = tq; }
    __syncthreads();
    const float S  = red[0] + red[1] + red[2] + red[3];
    const float SQ = red[4] + red[5] + red[6] + red[7];
    const float mu  = S * (1.f / C_);
    const float var = SQ * (1.f / C_) - mu * mu;
    const float r   = rsqrtf(var + 1e-5f);
    out[(size_t)p * C_ + tid] = (v - mu) * r * w[tid] + b[tid];
}

// ---------------------------------------------------------------------------
// Kernel 3: small patch GEMM  out[p][j] = act( in[p][:] . W[j][:] + bias[j] (+res) )
// W row-major with leading dim ldw (lets us address in_proj_w rows 512..767 and
// fuse_w columns 256..511 via pointer offset). TP patches per 256-thread block,
// thread j owns output channel j.
// ---------------------------------------------------------------------------
template <bool RELU, bool RES>
__global__ __launch_bounds__(256) void patch_gemm(
    const float* __restrict__ in, const float* __restrict__ W, int ldw,
    const float* __restrict__ bias, const float* __restrict__ res,
    float* __restrict__ out)
{
    constexpr int TP = 16;
    __shared__ float in_s[TP][C_ + 4];
    const int p0  = blockIdx.x * TP;
    const int tid = threadIdx.x;

    #pragma unroll
    for (int m = 0; m < TP; ++m)
        in_s[m][tid] = in[(size_t)(p0 + m) * C_ + tid];
    __syncthreads();

    float acc[TP];
    #pragma unroll
    for (int m = 0; m < TP; ++m) acc[m] = 0.f;

    const float* wrow = W + (size_t)tid * ldw;
    for (int k = 0; k < C_; k += 4) {
        const float4 w4 = *(const float4*)(wrow + k);
        #pragma unroll
        for (int m = 0; m < TP; ++m) {
            const float4 xv = *(const float4*)(&in_s[m][k]);   // broadcast LDS read
            acc[m] = fmaf(xv.x, w4.x, acc[m]);
            acc[m] = fmaf(xv.y, w4.y, acc[m]);
            acc[m] = fmaf(xv.z, w4.z, acc[m]);
            acc[m] = fmaf(xv.w, w4.w, acc[m]);
        }
    }

    const float bb = bias[tid];
    #pragma unroll
    for (int m = 0; m < TP; ++m) {
        float v = acc[m] + bb;
        if (RES)  v += res[(size_t)(p0 + m) * C_ + tid];
        if (RELU) v = fmaxf(v, 0.f);
        out[(size_t)(p0 + m) * C_ + tid] = v;
    }
}

// ---------------------------------------------------------------------------
// Kernel 4: main fused node kernel.
//   x = LN(orig; node_norm)           (computed in LDS)
//   out = relu( x @ Wx^T + pc[batch] ) + x     (Wx = fuse_w[:, 0:256], ld 512;
//                                               pc already contains fuse_b)
// 32 nodes per 256-thread block; thread j owns output channel j for all nodes.
// ---------------------------------------------------------------------------
__global__ __launch_bounds__(256) void main_fuse(
    const float* __restrict__ orig, const int* __restrict__ batch,
    const float* __restrict__ nw, const float* __restrict__ nb,
    const float* __restrict__ fuse_w, const float* __restrict__ pc,
    float* __restrict__ out)
{
    constexpr int TN    = 32;
    constexpr int LDS_W = C_ + 4;   // 260: keeps float4 alignment, spreads banks
    __shared__ float xs[TN][LDS_W];
    __shared__ float mu_s[TN], rs_s[TN];
    __shared__ int   pb[TN];

    const int n0  = blockIdx.x * TN;
    const int tid = threadIdx.x;

    // Stage the 32x256 tile (coalesced) + the 32 batch ids
    #pragma unroll
    for (int m = 0; m < TN; ++m)
        xs[m][tid] = orig[(size_t)(n0 + m) * C_ + tid];
    if (tid < TN) pb[tid] = batch[n0 + tid];
    __syncthreads();

    // LayerNorm stats: 8 threads per node (32 nodes x 8 lanes = 256 threads)
    {
        const int n = tid >> 3, l = tid & 7;
        float s = 0.f, sq = 0.f;
        #pragma unroll
        for (int i = 0; i < 32; ++i) {
            const float v = xs[n][l + 8 * i];
            s += v; sq += v * v;
        }
        #pragma unroll
        for (int off = 4; off > 0; off >>= 1) {
            s  += __shfl_xor(s,  off, 8);
            sq += __shfl_xor(sq, off, 8);
        }
        if (l == 0) {
            const float mu  = s * (1.f / C_);
            const float var = sq * (1.f / C_) - mu * mu;
            mu_s[n] = mu;
            rs_s[n] = rsqrtf(var + 1e-5f);
        }
    }
    __syncthreads();

    // Normalize column tid of every node, in place
    {
        const float w = nw[tid], b = nb[tid];
        #pragma unroll
        for (int m = 0; m < TN; ++m)
            xs[m][tid] = (xs[m][tid] - mu_s[m]) * rs_s[m] * w + b;
    }
    __syncthreads();

    // GEMM: acc[n] = x[n][:] . fuse_w[tid][0:256]
    float acc[TN];
    #pragma unroll
    for (int m = 0; m < TN; ++m) acc[m] = 0.f;

    const float* wrow = fuse_w + (size_t)tid * 512;   // leading dim 2C = 512
    for (int k = 0; k < C_; k += 4) {
        const float4 w4 = *(const float4*)(wrow + k);
        #pragma unroll
        for (int m = 0; m < TN; ++m) {
            const float4 xv = *(const float4*)(&xs[m][k]);   // broadcast LDS read
            acc[m] = fmaf(xv.x, w4.x, acc[m]);
            acc[m] = fmaf(xv.y, w4.y, acc[m]);
            acc[m] = fmaf(xv.z, w4.z, acc[m]);
            acc[m] = fmaf(xv.w, w4.w, acc[m]);
        }
    }

    // Epilogue: + pc[batch] (holds fuse_b), relu, + x, store
    #pragma unroll
    for (int m = 0; m < TN; ++m) {
        float v = acc[m] + pc[(size_t)pb[m] * C_ + tid];
        v = fmaxf(v, 0.f) + xs[m][tid];
        out[(size_t)(n0 + m) * C_ + tid] = v;
    }
}

// ---------------------------------------------------------------------------
extern "C" void kernel_launch(void* const* d_in, const int* in_sizes, int n_in,
                              void* d_out, int out_size, void* d_ws, size_t ws_size,
                              hipStream_t stream)
{
    const float* orig = (const float*)d_in[0];
    const float* dgf  = (const float*)d_in[1];
    const float* nnw  = (const float*)d_in[2];
    const float* nnb  = (const float*)d_in[3];
    const float* dnw  = (const float*)d_in[4];
    const float* dnb  = (const float*)d_in[5];
    const float* ipw  = (const float*)d_in[6];   // (768, 256)
    const float* ipb  = (const float*)d_in[7];   // (768,)
    const float* opw  = (const float*)d_in[8];   // (256, 256)
    const float* opb  = (const float*)d_in[9];
    const float* fnw  = (const float*)d_in[10];
    const float* fnb  = (const float*)d_in[11];
    const float* l1w  = (const float*)d_in[12];
    const float* l1b  = (const float*)d_in[13];
    const float* l2w  = (const float*)d_in[14];
    const float* l2b  = (const float*)d_in[15];
    const float* fw   = (const float*)d_in[16];  // (256, 512)
    const float* fb   = (const float*)d_in[17];
    const int*   batch = (const int*)d_in[18];
    float* out = (float*)d_out;

    float* B0 = (float*)d_ws;            // 4 MB each
    float* B1 = B0 + (size_t)P_ * C_;
    float* B2 = B1 + (size_t)P_ * C_;

    // g = LN(segment_mean(dg_features)) -> B0
    seg_mean_ln<<<P_, 256, 0, stream>>>(dgf, batch, dnw, dnb, B0);
    // v = g @ Wv^T + bv  (rows 512..767 of in_proj) -> B1
    patch_gemm<false, false><<<P_ / 16, 256, 0, stream>>>(B0, ipw + (size_t)512 * C_, C_, ipb + 512, nullptr, B1);
    // attn = v @ out_proj^T + out_proj_b -> B2
    patch_gemm<false, false><<<P_ / 16, 256, 0, stream>>>(B1, opw, C_, opb, nullptr, B2);
    // y = LN(attn; ffn_norm) -> B0
    patch_ln<<<P_, 256, 0, stream>>>(B2, fnw, fnb, B0);
    // h = relu(y @ lin1^T + b1) -> B1
    patch_gemm<true, false><<<P_ / 16, 256, 0, stream>>>(B0, l1w, C_, l1b, nullptr, B1);
    // dg = h @ lin2^T + b2 + attn -> B0
    patch_gemm<false, true><<<P_ / 16, 256, 0, stream>>>(B1, l2w, C_, l2b, B2, B0);
    // pc = dg @ Wp^T + fuse_b  (Wp = fuse_w[:, 256:512], ld 512) -> B1
    patch_gemm<false, false><<<P_ / 16, 256, 0, stream>>>(B0, fw + 256, 512, fb, nullptr, B1);
    // out = relu(LN(orig) @ Wx^T + pc[batch]) + LN(orig)
    main_fuse<<<N_ / 32, 256, 0, stream>>>(orig, batch, nnw, nnb, fw, B1, out);
}